// Round 10
// baseline (348.500 us; speedup 1.0000x reference)
//
#include <hip/hip_runtime.h>
#include <stdint.h>

// Problem dims (fixed by the reference):
//   B=8192, P=2, L1=L2=9, N=25, F=128
//   x1: [B,2,9,128] f32, x2: [B,2,9,128] f32, cg: [9,9,25] f32
//   out: [B,1,2,25,128] f32
//
// out[b,0,0,n,f] = sum_{l,m} cg[l,m,n]*(x1e[l]*x2o[m] + x1o[l]*x2e[m])
// out[b,0,1,n,f] = sum_{l,m} cg[l,m,n]*(x1e[l]*x2o[m] + x1o[l]*x2o[m])
// (reference's eoo==eee bug reproduced: both channels share the x1e*x2o term)
//
// Round-10: v_dot2_f32_f16 formulation. Corrected machine model: fp32 VALU
// issue floor is ~57us (4050 v_fma_f32/thread, 2cyc each, 16 waves/SIMD of
// work; pk_fma_f32 is 4cyc => no gain, confirmed null in round 7). fdot2
// does 2 f16 MACs/instr at full rate with FP32 ACCUMULATE -> floor ~32us,
// below the ~45us memory floor. K-axis (l,m) flattened to 81, processed as
// 41 pairs (last padded with zero). cg repacked by prep kernel into f16
// pairs on the SMEM path (addrspace(4), 16B-aligned rows); s-values
// computed fp32 then packed with v_cvt_pkrtz. Retains round-8's full
// unroll + __launch_bounds__(256,4) + NT stores.

#define B_DIM 8192
#define F_DIM 128
#define L_DIM 9
#define N_DIM 25
#define LM_DIM 81
#define KPAIR 41                 // 40 full (lm) pairs + 1 zero-padded
#define CROW 28                  // row stride in u32: 112B, 16B-aligned

typedef const __attribute__((address_space(4))) uint32_t* cu32p4;
using h2_t = decltype(__builtin_amdgcn_cvt_pkrtz(0.0f, 0.0f));  // <2 x half>

__device__ __align__(16) uint32_t g_cgp2[KPAIR * CROW];  // 4592 B

__global__ __launch_bounds__(256) void cg_prep(const float* __restrict__ cg) {
    // pack cg[lm][n] (lm = l*9+m, row-major [81][25]) into f16 pairs:
    // g_cgp2[a*CROW + n] = {f16(cg[2a][n]) , f16(cg[2a+1][n])} (lo,hi)
    for (int i = threadIdx.x; i < KPAIR * CROW; i += 256) {
        const int a = i / CROW;
        const int n = i - a * CROW;
        uint32_t packed = 0;
        if (n < N_DIM) {
            const int lm0 = 2 * a, lm1 = 2 * a + 1;
            _Float16 h0 = (_Float16)cg[lm0 * N_DIM + n];          // lm0 <= 80 always
            _Float16 h1 = (lm1 < LM_DIM) ? (_Float16)cg[lm1 * N_DIM + n]
                                         : (_Float16)0.0f;
            packed = (uint32_t)__builtin_bit_cast(uint16_t, h0) |
                     ((uint32_t)__builtin_bit_cast(uint16_t, h1) << 16);
        }
        g_cgp2[i] = packed;
    }
}

__global__ __launch_bounds__(256, 4) void tp_kernel(
    const float* __restrict__ x1,
    const float* __restrict__ x2,
    float* __restrict__ out)
{
    const int g = blockIdx.x * 256 + threadIdx.x;
    const int b = g >> 7;      // g / F_DIM
    const int f = g & 127;     // g % F_DIM

    const float* x1b = x1 + (size_t)b * 2 * L_DIM * F_DIM + f;
    const float* x2b = x2 + (size_t)b * 2 * L_DIM * F_DIM + f;

    // all parity slices up-front: 36 outstanding loads, scheduler hides them
    float x1e[L_DIM], x1o[L_DIM], x2e[L_DIM], x2o[L_DIM];
#pragma unroll
    for (int l = 0; l < L_DIM; ++l) {
        x1e[l] = x1b[l * F_DIM];
        x1o[l] = x1b[(L_DIM + l) * F_DIM];
        x2e[l] = x2b[l * F_DIM];
        x2o[l] = x2b[(L_DIM + l) * F_DIM];
    }

    float acc0[N_DIM], acc1[N_DIM];
#pragma unroll
    for (int n = 0; n < N_DIM; ++n) { acc0[n] = 0.0f; acc1[n] = 0.0f; }

    // cg f16-pairs via constant addrspace -> SMEM pipe (scalar cache, 4.6KB)
    const cu32p4 cgp = (cu32p4)(uintptr_t)&g_cgp2[0];

    // FULL unroll: 41 pairs x (6 fma/mul + 2 cvt_pkrtz + 50 fdot2)
#pragma unroll
    for (int a = 0; a < KPAIR; ++a) {
        const int lm0 = 2 * a, lm1 = 2 * a + 1;        // compile-time
        const int l0 = lm0 / L_DIM, m0 = lm0 % L_DIM;
        // s for lm0
        const float t0  = x1e[l0] * x2o[m0];
        const float s0a = fmaf(x1o[l0], x2e[m0], t0);  // ch0: eee+ooe
        const float s1a = fmaf(x1o[l0], x2o[m0], t0);  // ch1: eoo+oeo
        // s for lm1 (zero for the pad pair)
        float s0b = 0.0f, s1b = 0.0f;
        if (lm1 < LM_DIM) {
            const int l1 = lm1 / L_DIM, m1 = lm1 % L_DIM;
            const float t1 = x1e[l1] * x2o[m1];
            s0b = fmaf(x1o[l1], x2e[m1], t1);
            s1b = fmaf(x1o[l1], x2o[m1], t1);
        }
        const h2_t s0p = __builtin_amdgcn_cvt_pkrtz(s0a, s0b);  // {lo,hi}
        const h2_t s1p = __builtin_amdgcn_cvt_pkrtz(s1a, s1b);
#pragma unroll
        for (int n = 0; n < N_DIM; ++n) {
            const uint32_t cv = cgp[a * CROW + n];
            const h2_t ch = __builtin_bit_cast(h2_t, cv);
#if __has_builtin(__builtin_amdgcn_fdot2)
            acc0[n] = __builtin_amdgcn_fdot2(ch, s0p, acc0[n], false);
            acc1[n] = __builtin_amdgcn_fdot2(ch, s1p, acc1[n], false);
#else
            acc0[n] = fmaf((float)ch[0], (float)s0p[0],
                      fmaf((float)ch[1], (float)s0p[1], acc0[n]));
            acc1[n] = fmaf((float)ch[0], (float)s1p[0],
                      fmaf((float)ch[1], (float)s1p[1], acc1[n]));
#endif
        }
    }

    // out[b,0,ch,n,f] -> ((b*2 + ch)*25 + n)*128 + f
    float* ob = out + (size_t)b * 2 * N_DIM * F_DIM + f;
#pragma unroll
    for (int n = 0; n < N_DIM; ++n) {
        __builtin_nontemporal_store(acc0[n], ob + n * F_DIM);
        __builtin_nontemporal_store(acc1[n], ob + (N_DIM + n) * F_DIM);
    }
}

extern "C" void kernel_launch(void* const* d_in, const int* in_sizes, int n_in,
                              void* d_out, int out_size, void* d_ws, size_t ws_size,
                              hipStream_t stream) {
    (void)in_sizes; (void)n_in; (void)out_size; (void)d_ws; (void)ws_size;
    const float* x1 = (const float*)d_in[0];
    const float* x2 = (const float*)d_in[1];
    const float* cg = (const float*)d_in[2];
    float* out = (float*)d_out;

    // 1) repack cg into f16-pair table (stream-ordered before main kernel)
    cg_prep<<<1, 256, 0, stream>>>(cg);

    // 2) main: B*F threads, one (b,f) each: 8192*128/256 = 4096 blocks
    const int threads = 256;
    const int blocks  = (B_DIM * F_DIM) / threads;
    tp_kernel<<<blocks, threads, 0, stream>>>(x1, x2, out);
}

// Round 11
// 323.281 us; speedup vs baseline: 1.0780x; 1.0780x over previous
//
#include <hip/hip_runtime.h>
#include <stdint.h>

// Problem dims (fixed by the reference):
//   B=8192, P=2, L1=L2=9, N=25, F=128
//   x1: [B,2,9,128] f32, x2: [B,2,9,128] f32, cg: [9,9,25] f32
//   out: [B,1,2,25,128] f32
//
// out[b,0,0,n,f] = sum_{lm} cg[lm][n]*(x1e[l]*x2o[m] + x1o[l]*x2e[m])
// out[b,0,1,n,f] = sum_{lm} cg[lm][n]*(x1e[l]*x2o[m] + x1o[l]*x2o[m])
// (reference's eoo==eee bug reproduced: both channels share the x1e*x2o term)
//
// Round-11: MFMA formulation. Measured r10: fdot2 is half-rate -> every
// VALU formulation has a ~57-60us issue floor, serialized with a ~60us
// memory floor (130us total). MFMA removes the VALU floor: per b the
// contraction is a GEMM out[n][f] = sum_k cgT[n][k] * S[k][f], K=81->96,
// M=25->32 (2 tiles), N=f=128 (8 tiles), x2 channels.
//  - one block per b; 256 thr compute S in fp32 (3 FMA/k, split k across
//    2 thread-halves), pack f16 (cvt_pkrtz) -> LDS [f][k] stride 208B
//    (2-way bank conflicts only = free).
//  - A-side (cg) packed ONCE by prep kernel into exact per-lane fragment
//    order (A[row=n=lane&15][k=kstep*32+(lane>>4)*8+i], zero-padded);
//    6 KB, L2-resident, loaded as 6 x uint4 per lane.
//  - 4 waves x 24 v_mfma_f32_16x16x32_f16 (wave = one ch x 4 f-tiles);
//    C/D: col=lane&15 (f), row=(lane>>4)*4+reg (n) -> stores are 4x64B
//    fully-written segments, n>=25 predicated off.
//  - f16 inputs + fp32 accumulate: same precision as round 10 (absmax
//    0.5, passed).

#define B_DIM 8192
#define F_DIM 128
#define L_DIM 9
#define N_DIM 25
#define K_DIM 81
#define ROW_U32 52                   // LDS f-row stride in u32 (208 B)
#define CH_U32 (F_DIM * ROW_U32)     // 6656 u32 per channel

typedef _Float16 half8 __attribute__((ext_vector_type(8)));
typedef _Float16 half2v __attribute__((ext_vector_type(2)));
typedef float f32x4 __attribute__((ext_vector_type(4)));

__device__ __align__(16) uint4 g_fragA[2 * 3 * 64];   // [mtile][kstep][lane]

__global__ __launch_bounds__(256) void cg_prep(const float* __restrict__ cg) {
    // Pack cgT[n][k] (= cg[k*25+n]) into per-lane A-fragment order for
    // v_mfma_f32_16x16x32_f16: lane holds row n=(lane&15), k = kstep*32 +
    // (lane>>4)*8 + i, i=0..7, as 4 u32 (f16 pairs). Zero-pad k>=81, n>=25.
    for (int e = threadIdx.x; e < 2 * 3 * 64; e += 256) {
        const int fid  = e >> 6;                 // 0..5
        const int lane = e & 63;
        const int mtile = fid / 3, kstep = fid - 3 * mtile;
        const int n     = mtile * 16 + (lane & 15);
        const int kbase = kstep * 32 + (lane >> 4) * 8;
        uint32_t w[4];
        for (int j = 0; j < 4; ++j) {
            const int k0 = kbase + 2 * j, k1 = k0 + 1;
            const float v0 = (k0 < K_DIM && n < N_DIM) ? cg[k0 * N_DIM + n] : 0.0f;
            const float v1 = (k1 < K_DIM && n < N_DIM) ? cg[k1 * N_DIM + n] : 0.0f;
            w[j] = __builtin_bit_cast(uint32_t, __builtin_amdgcn_cvt_pkrtz(v0, v1));
        }
        g_fragA[e] = make_uint4(w[0], w[1], w[2], w[3]);
    }
}

__global__ __launch_bounds__(256, 3) void tp_kernel(
    const float* __restrict__ x1,
    const float* __restrict__ x2,
    float* __restrict__ out)
{
    __shared__ uint32_t S[2 * CH_U32];           // 53248 B: S[ch][f][k] f16
    const int b = blockIdx.x;
    const int t = threadIdx.x;
    const int lane = t & 63;

    // A-fragments (cg side): same for all blocks, tiny, L2-resident.
    uint4 afr[2][3];
#pragma unroll
    for (int mt = 0; mt < 2; ++mt)
#pragma unroll
        for (int ks = 0; ks < 3; ++ks)
            afr[mt][ks] = g_fragA[(mt * 3 + ks) * 64 + lane];

    // ---- phase 1: build S[ch][f][k] in LDS ----
    const int f     = t & 127;
    const int khalf = t >> 7;                    // wave-uniform (waves 0,1 vs 2,3)

    const float* x1b = x1 + (size_t)b * (2 * L_DIM * F_DIM) + f;
    const float* x2b = x2 + (size_t)b * (2 * L_DIM * F_DIM) + f;

    float x2e[L_DIM], x2o[L_DIM];
#pragma unroll
    for (int m = 0; m < L_DIM; ++m) {
        x2e[m] = x2b[m * F_DIM];
        x2o[m] = x2b[(L_DIM + m) * F_DIM];
    }

    uint32_t* Srow0 = S + f * ROW_U32 + khalf * 24;   // ch0, this thread's k-half
    uint32_t* Srow1 = Srow0 + CH_U32;                  // ch1

    if (khalf == 0) {                            // k = 0..47 -> l = 0..5
        float x1e[6], x1o[6];
#pragma unroll
        for (int l = 0; l < 6; ++l) {
            x1e[l] = x1b[l * F_DIM];
            x1o[l] = x1b[(L_DIM + l) * F_DIM];
        }
#pragma unroll
        for (int j = 0; j < 12; ++j) {           // 4 k per iter -> one uint2/ch
            float s0[4], s1[4];
#pragma unroll
            for (int kk = 0; kk < 4; ++kk) {
                const int k = 4 * j + kk;        // compile-time
                const int l = k / 9, m = k % 9;
                const float tt = x1e[l] * x2o[m];
                s0[kk] = fmaf(x1o[l], x2e[m], tt);   // ch0: eee+ooe
                s1[kk] = fmaf(x1o[l], x2o[m], tt);   // ch1: eoo+oeo
            }
            uint2 w0, w1;
            w0.x = __builtin_bit_cast(uint32_t, __builtin_amdgcn_cvt_pkrtz(s0[0], s0[1]));
            w0.y = __builtin_bit_cast(uint32_t, __builtin_amdgcn_cvt_pkrtz(s0[2], s0[3]));
            w1.x = __builtin_bit_cast(uint32_t, __builtin_amdgcn_cvt_pkrtz(s1[0], s1[1]));
            w1.y = __builtin_bit_cast(uint32_t, __builtin_amdgcn_cvt_pkrtz(s1[2], s1[3]));
            *reinterpret_cast<uint2*>(Srow0 + 2 * j) = w0;
            *reinterpret_cast<uint2*>(Srow1 + 2 * j) = w1;
        }
    } else {                                     // k = 48..95 -> l = 5..8, pad>80
        float x1e[4], x1o[4];
#pragma unroll
        for (int l = 0; l < 4; ++l) {
            x1e[l] = x1b[(5 + l) * F_DIM];
            x1o[l] = x1b[(L_DIM + 5 + l) * F_DIM];
        }
#pragma unroll
        for (int j = 0; j < 12; ++j) {
            float s0[4], s1[4];
#pragma unroll
            for (int kk = 0; kk < 4; ++kk) {
                const int k = 48 + 4 * j + kk;   // compile-time
                if (k < K_DIM) {
                    const int l = k / 9 - 5, m = k % 9;
                    const float tt = x1e[l] * x2o[m];
                    s0[kk] = fmaf(x1o[l], x2e[m], tt);
                    s1[kk] = fmaf(x1o[l], x2o[m], tt);
                } else { s0[kk] = 0.0f; s1[kk] = 0.0f; }
            }
            uint2 w0, w1;
            w0.x = __builtin_bit_cast(uint32_t, __builtin_amdgcn_cvt_pkrtz(s0[0], s0[1]));
            w0.y = __builtin_bit_cast(uint32_t, __builtin_amdgcn_cvt_pkrtz(s0[2], s0[3]));
            w1.x = __builtin_bit_cast(uint32_t, __builtin_amdgcn_cvt_pkrtz(s1[0], s1[1]));
            w1.y = __builtin_bit_cast(uint32_t, __builtin_amdgcn_cvt_pkrtz(s1[2], s1[3]));
            *reinterpret_cast<uint2*>(Srow0 + 2 * j) = w0;
            *reinterpret_cast<uint2*>(Srow1 + 2 * j) = w1;
        }
    }
    __syncthreads();

    // ---- phase 2: MFMA. wave wv: ch = wv&1, f-quarter fq = wv>>1 ----
    const int wv = t >> 6;
    const int ch = wv & 1;
    const int fq = wv >> 1;                      // ntiles fq*4 .. fq*4+3
    const int r  = lane & 15, g4 = lane >> 4;

    f32x4 acc[2][4];
#pragma unroll
    for (int mt = 0; mt < 2; ++mt)
#pragma unroll
        for (int nt = 0; nt < 4; ++nt)
            acc[mt][nt] = (f32x4)(0.0f);

    const uint32_t* Sch = S + ch * CH_U32;
#pragma unroll
    for (int nt = 0; nt < 4; ++nt) {
        const int ntile = fq * 4 + nt;
        // B-frag: col f = ntile*16 + r, k = kstep*32 + g4*8 + i (16B read)
        const uint32_t* base = Sch + (ntile * 16 + r) * ROW_U32 + g4 * 4;
#pragma unroll
        for (int ks = 0; ks < 3; ++ks) {
            const uint4 bw = *reinterpret_cast<const uint4*>(base + ks * 16);
            const half8 bh = __builtin_bit_cast(half8, bw);
#pragma unroll
            for (int mt = 0; mt < 2; ++mt) {
                const half8 ah = __builtin_bit_cast(half8, afr[mt][ks]);
                acc[mt][nt] = __builtin_amdgcn_mfma_f32_16x16x32_f16(
                    ah, bh, acc[mt][nt], 0, 0, 0);
            }
        }
    }

    // ---- stores: out[b,0,ch,n,f]; C/D col=r (f), row=g4*4+j (n) ----
    float* ob = out + (size_t)b * (2 * N_DIM * F_DIM) + (size_t)ch * (N_DIM * F_DIM);
#pragma unroll
    for (int mt = 0; mt < 2; ++mt)
#pragma unroll
        for (int nt = 0; nt < 4; ++nt) {
            const int fcol = (fq * 4 + nt) * 16 + r;
#pragma unroll
            for (int j = 0; j < 4; ++j) {
                const int n = mt * 16 + g4 * 4 + j;
                if (n < N_DIM)
                    __builtin_nontemporal_store(acc[mt][nt][j], ob + n * F_DIM + fcol);
            }
        }
}

extern "C" void kernel_launch(void* const* d_in, const int* in_sizes, int n_in,
                              void* d_out, int out_size, void* d_ws, size_t ws_size,
                              hipStream_t stream) {
    (void)in_sizes; (void)n_in; (void)out_size; (void)d_ws; (void)ws_size;
    const float* x1 = (const float*)d_in[0];
    const float* x2 = (const float*)d_in[1];
    const float* cg = (const float*)d_in[2];
    float* out = (float*)d_out;

    // 1) pack cg into MFMA A-fragment order (stream-ordered before main)
    cg_prep<<<1, 256, 0, stream>>>(cg);

    // 2) main: one block per b
    tp_kernel<<<B_DIM, 256, 0, stream>>>(x1, x2, out);
}